// Round 9
// baseline (552.918 us; speedup 1.0000x reference)
//
#include <hip/hip_runtime.h>

#define NB 8
#define TQv 2048
#define TKv 2048
#define FD 1024
#define HD 1024

typedef __attribute__((ext_vector_type(8))) short short8;
typedef __attribute__((ext_vector_type(8))) _Float16 half8;
typedef __attribute__((ext_vector_type(4))) float f32x4;

// round-to-nearest-even fp32 -> bf16 (finite inputs only)
__device__ __forceinline__ short f2bf(float f) {
    union { float f; unsigned u; } v; v.f = f;
    unsigned r = v.u + 0x7FFFu + ((v.u >> 16) & 1u);
    return (short)(r >> 16);
}

__device__ __forceinline__ half8 as_h8(short8 v) {
    union { short8 s; half8 h; } u; u.s = v; return u.h;
}

// async 16B global -> LDS (global_load_lds_dwordx4); LDS dest = wave-uniform base + lane*16
__device__ __forceinline__ void async16(const short* g, short* l) {
    __builtin_amdgcn_global_load_lds(
        (const __attribute__((address_space(1))) unsigned int*)g,
        (__attribute__((address_space(3))) unsigned int*)l, 16, 0, 0);
}

// 32-bit LDS byte offset of a generic pointer into __shared__
__device__ __forceinline__ unsigned lds_off(void* p) {
    return (unsigned)(unsigned long long)(__attribute__((address_space(3))) char*)p;
}

#define BAR  __builtin_amdgcn_s_barrier()
#define SP1  __builtin_amdgcn_s_setprio(1)
#define SP0  __builtin_amdgcn_s_setprio(0)
#define SCB  __builtin_amdgcn_sched_barrier(0)
#define VMCNT(N) asm volatile("s_waitcnt vmcnt(" #N ")" ::: "memory")
#define LGKC(N)  asm volatile("s_waitcnt lgkmcnt(" #N ")" ::: "memory")

// ds_read_b128 as INLINE ASM (opaque to the memory legalizer; no auto vmcnt(0)).
// Volatile asm keeps DSR/LGKC/BAR relative order; MFMA intrinsics may interleave
// freely between SCB fences — that interleave IS the read∥MFMA overlap we want.
#define DSR(dst, addr, OFS) \
    asm volatile("ds_read_b128 %0, %1 offset:" OFS : "=v"(dst) : "v"(addr))

// ========= 256x256 read-ahead GEMM core (R9: reads overlap MFMA) =========
// NT: C[m][n] = sum_k A[m][k]*B[n][k]. 512 thr = 8 waves (2M x 4N); wave C = 128x64
// = acc[8][4] f32x4; 16x16x32 MFMA; BK=64; K-tiles double-buffered in 128 KiB LDS
// with the verified XOR swizzle (SQ_LDS_BANK_CONFLICT == 0).
// R9 MODEL: per iter LDS reads = 384 KB/CU = ~1500 cyc @256B/clk vs MFMA 931 cyc/SIMD
// -> 62% ceiling (= m201's measured MfmaUtil). Pre-R9, reads and MFMA serialized per
// phase (31%). Now reads for phase p+1 are issued AFTER phase p's opening barrier and
// interleave with phase p's MFMA cluster; consumption waits at next phase's LGKC(0).
// 6 segments/iter, 12 barriers. Stage ledger (tiles a=2i->buf0, b=a+1->buf1):
//   S1: B(1,0)  S2: B(1,1)  S3: A(0,0)+A(0,1)+VMCNT(4)
//   S4: B(0,0)  S5: B(0,1)  S6: A(1,0)+A(1,1)+VMCNT(4)
// Read schedule (each issued post-opening-barrier, consumed next segment):
//   prologue: aQ0,bQ0(buf0) | S1: aQ1(0) | S2: bQ1(0) | S3: aQ0,bQ0(buf1)
//   S4: aQ1(1) | S5: bQ1(1) | S6: aQ0,bQ0(buf0-next)
// MFMA: S1 C00(0) | S2 C10(0),C01(0) (mid LGKC) | S3 C11(0) | S4-S6 mirror buf1.
// RAW(vmcnt): S3's VMCNT(4): outstanding = S6A-prev(4)+S1B(2)+S2B(2)+S3A(4)=12 ->
//   drains S6Aprev,S1B,S2B; post-bar reads aQ(1)[staged S6-prev] + bQ0(1)[S1] safe.
//   S6's VMCNT(4): outstanding = S3A+S4B+S5B+S6A=12 -> drains S3A,S4B,S5B; post-bar
//   reads of buf0 (A@S3, B-half0@S4) safe. Every read sits after a barrier that
//   follows ALL waves' covering VMCNT (cross-wave publication).
// WAR(lds): every staged region's prior reads are lgkm-drained >=1 barrier earlier.
// Last iter: S3 VMCNT(0) (buf1 reads still needed); S6: no stage/reads.
#define RD_ALO(BF) { DSR(aQ0[0][0], adA0[BF], "0");    DSR(aQ0[0][1], adA1[BF], "0"); \
                     DSR(aQ0[1][0], adA0[BF], "2048"); DSR(aQ0[1][1], adA1[BF], "2048"); \
                     DSR(aQ0[2][0], adA0[BF], "4096"); DSR(aQ0[2][1], adA1[BF], "4096"); \
                     DSR(aQ0[3][0], adA0[BF], "6144"); DSR(aQ0[3][1], adA1[BF], "6144"); }
#define RD_AHI(BF) { DSR(aQ1[0][0], adA0[BF], "8192");  DSR(aQ1[0][1], adA1[BF], "8192"); \
                     DSR(aQ1[1][0], adA0[BF], "10240"); DSR(aQ1[1][1], adA1[BF], "10240"); \
                     DSR(aQ1[2][0], adA0[BF], "12288"); DSR(aQ1[2][1], adA1[BF], "12288"); \
                     DSR(aQ1[3][0], adA0[BF], "14336"); DSR(aQ1[3][1], adA1[BF], "14336"); }
#define RD_BLO(BF) { DSR(bQ0[0][0], adB0[BF], "0");    DSR(bQ0[0][1], adB1[BF], "0"); \
                     DSR(bQ0[1][0], adB0[BF], "2048"); DSR(bQ0[1][1], adB1[BF], "2048"); }
#define RD_BHI(BF) { DSR(bQ1[0][0], adB0[BF], "4096"); DSR(bQ1[0][1], adB1[BF], "4096"); \
                     DSR(bQ1[1][0], adB0[BF], "6144"); DSR(bQ1[1][1], adB1[BF], "6144"); }

#define QMFMA(AQ, BQ, MO, NO) { \
    _Pragma("unroll") for (int ks = 0; ks < 2; ++ks) \
    _Pragma("unroll") for (int f = 0; f < 4; ++f) \
    _Pragma("unroll") for (int n = 0; n < 2; ++n) { \
        if constexpr (F16) \
            acc[(MO)+f][(NO)+n] = __builtin_amdgcn_mfma_f32_16x16x32_f16( \
                as_h8(AQ[f][ks]), as_h8(BQ[n][ks]), acc[(MO)+f][(NO)+n], 0, 0, 0); \
        else \
            acc[(MO)+f][(NO)+n] = __builtin_amdgcn_mfma_f32_16x16x32_bf16( \
                AQ[f][ks], BQ[n][ks], acc[(MO)+f][(NO)+n], 0, 0, 0); } }

// stage one half-tile (2 x async16); REL/tofs in shorts (k-units)
#define STG_A(BF, H, REL) { \
    async16(gaBase + sH[2*(H)+0] + tofs + (REL), lbase + (BF)*32768 + (H)*8192); \
    async16(gaBase + sH[2*(H)+1] + tofs + (REL), lbase + (BF)*32768 + (H)*8192 + 4096); }
#define STG_B(BF, H, REL) { \
    async16(gbBase + sH[2*(H)+0] + tofs + (REL), lbase + (BF)*32768 + 16384 + (H)*8192); \
    async16(gbBase + sH[2*(H)+1] + tofs + (REL), lbase + (BF)*32768 + 16384 + (H)*8192 + 4096); }

template <bool F16>
__device__ __forceinline__ void gemm256_core(const short* __restrict__ A,
                                             const short* __restrict__ B,
                                             int ld, int K, char* smem,
                                             f32x4 acc[8][4], int tid) {
    const int wid = tid >> 6, lane = tid & 63;
    const int wm = wid >> 2, wn = wid & 3;
    const int l15 = lane & 15;

    // staging: per-thread global base + SGPR row-window offsets
    const int kc8 = ((lane & 7) ^ (lane >> 3)) * 8;
    const short* gaBase = A + (size_t)(wid * 8 + (lane >> 3)) * ld + kc8;
    const short* gbBase = B + (size_t)(wid * 8 + (lane >> 3)) * ld + kc8;
    size_t sH[4];
#pragma unroll
    for (int k = 0; k < 4; ++k) sH[k] = (size_t)k * 64 * ld;
    short* lbase = (short*)smem + wid * 512;

    // loop-invariant 32-bit LDS read addresses (ks0/ks1 swizzled chunk, per buf)
    const int o0 = (((lane >> 4)    ) ^ (lane & 7)) * 16;
    const int o1 = (((lane >> 4) + 4) ^ (lane & 7)) * 16;
    unsigned aB_ = lds_off(smem) + wm * 16384 + l15 * 128;
    unsigned bB_ = lds_off(smem) + 32768 + (wn >> 1) * 16384 + (wn & 1) * 8192 + l15 * 128;
    unsigned adA0[2] = { aB_ + o0, aB_ + o0 + 65536u };
    unsigned adA1[2] = { aB_ + o1, aB_ + o1 + 65536u };
    unsigned adB0[2] = { bB_ + o0, bB_ + o0 + 65536u };
    unsigned adB1[2] = { bB_ + o1, bB_ + o1 + 65536u };

    int tofs = 0;
    // prologue: tile0 full -> buf0, tile1 A halves -> buf1; then first reads
    STG_A(0, 0, 0); STG_A(0, 1, 0); STG_B(0, 0, 0); STG_B(0, 1, 0);
    STG_A(1, 0, 64); STG_A(1, 1, 64);
    SCB; VMCNT(4); BAR; SCB;

    short8 aQ0[4][2], aQ1[4][2], bQ0[2][2], bQ1[2][2];
    RD_ALO(0); RD_BLO(0);              // consumed at S1's LGKC(0)
    const int niter = K >> 7;
    for (int it = 0; it < niter; ++it) {
        const bool nl = (it != niter - 1);
        // S1: C00(buf0) ∥ read aQ1(0)
        STG_B(1, 0, 64);
        SCB; BAR; LGKC(0); SCB;
        RD_AHI(0);
        SP1; QMFMA(aQ0, bQ0, 0, 0); SP0; SCB; BAR; SCB;
        // S2: C10(buf0), mid-LGKC, C01(buf0) ∥ read bQ1(0)
        STG_B(1, 1, 64);
        SCB; BAR; LGKC(0); SCB;
        RD_BHI(0);
        SP1; QMFMA(aQ1, bQ0, 4, 0); SP0;
        LGKC(0); SCB;
        SP1; QMFMA(aQ0, bQ1, 0, 2); SP0; SCB; BAR; SCB;
        // S3: C11(buf0) ∥ read aQ0,bQ0 (buf1)
        if (nl) { STG_A(0, 0, 128); STG_A(0, 1, 128); SCB; VMCNT(4); }
        else    { SCB; VMCNT(0); }
        BAR; SCB;
        RD_ALO(1); RD_BLO(1);
        SP1; QMFMA(aQ1, bQ1, 4, 2); SP0; SCB; BAR; SCB;
        // S4: C00(buf1) ∥ read aQ1(1)
        if (nl) STG_B(0, 0, 128);
        SCB; BAR; LGKC(0); SCB;
        RD_AHI(1);
        SP1; QMFMA(aQ0, bQ0, 0, 0); SP0; SCB; BAR; SCB;
        // S5: C10(buf1), mid-LGKC, C01(buf1) ∥ read bQ1(1)
        if (nl) STG_B(0, 1, 128);
        SCB; BAR; LGKC(0); SCB;
        RD_BHI(1);
        SP1; QMFMA(aQ1, bQ0, 4, 0); SP0;
        LGKC(0); SCB;
        SP1; QMFMA(aQ0, bQ1, 0, 2); SP0; SCB; BAR; SCB;
        // S6: C11(buf1) ∥ read aQ0,bQ0 (buf0-next)
        if (nl) { STG_A(1, 0, 192); STG_A(1, 1, 192); SCB; VMCNT(4); }
        BAR; SCB;
        if (nl) { RD_ALO(0); RD_BLO(0); }
        SP1; QMFMA(aQ1, bQ1, 4, 2); SP0; SCB; BAR; SCB;
        tofs += 128;
    }
}

// C/D layout per 16x16x32 frag (m89/m91): col = lane&15, row = 4*(lane>>4) + r
// global: row = tile_m + wm*128 + m*16 + 4*(lane>>4) + r ; col = tile_n + wn*64 + n*16 + (lane&15)

// ---- R9 merged prep: maskbits (int4+shfl, BW-bound) first, convert 64B/thr, wtrans ----
#define MB_BLKS   2048
#define CONV_BLKS 8192
#define CONV_END  (MB_BLKS + CONV_BLKS)
__global__ __launch_bounds__(256) void prep_kernel(const float* __restrict__ q,
                                                   const float* __restrict__ e,
                                                   const float* __restrict__ Wq,
                                                   const float* __restrict__ Wk,
                                                   const float* __restrict__ Wv,
                                                   const int* __restrict__ mask,
                                                   short* __restrict__ xq,
                                                   short* __restrict__ xe,
                                                   short* __restrict__ Wt,
                                                   unsigned long long* __restrict__ Mbits,
                                                   float* __restrict__ L) {
    __shared__ float tile[32][33];
    int bid = blockIdx.x, tid = threadIdx.x;
    if (bid < MB_BLKS) {
        // maskbits: lane loads int4 (16 B, coalesced 1 KB/wave), nibble of 4 compare
        // bits, then 16-lane-segmented shfl_xor OR-reduce assembles each u64 word.
        // Word w bits: int w*64+p -> bit p; lane l covers ints 4l..4l+3 of the 256-int
        // chunk => word (i*4 + (l>>4)), bits 4*(l&15)+j.  Replaces 4 dword loads + 4
        // wave-ballots (latency-chained) with 1 load + VALU (BW-bound).
        int lane = tid & 63;
        if (bid < 64) L[bid * 256 + tid] = 0.f;
        int g = bid * 4 + (tid >> 6);
        const int4* mp = (const int4*)(mask + (size_t)g * 64 * 64);
        unsigned long long* op = Mbits + (size_t)g * 64;
#pragma unroll 4
        for (int i = 0; i < 16; ++i) {
            int4 v = mp[i * 64 + lane];
            unsigned nib = (v.x != 0 ? 1u : 0u) | (v.y != 0 ? 2u : 0u)
                         | (v.z != 0 ? 4u : 0u) | (v.w != 0 ? 8u : 0u);
            unsigned long long val = (unsigned long long)nib << (4 * (lane & 15));
            val |= __shfl_xor(val, 1);
            val |= __shfl_xor(val, 2);
            val |= __shfl_xor(val, 4);
            val |= __shfl_xor(val, 8);
            if ((lane & 15) == 0) op[i * 4 + (lane >> 4)] = val;
        }
    } else if (bid < CONV_END) {
        // convert: 16 floats/thread (64 B read, 32 B written)
        int cb = bid - MB_BLKS;
        size_t i = (size_t)(cb & 4095) * 256 + tid;
        const float* src = (cb >> 12) ? e : q;
        short* dst = (cb >> 12) ? xe : xq;
        const float4* s4 = (const float4*)src + i * 4;
        float4 a = s4[0], b = s4[1], c = s4[2], d = s4[3];
        short8 v0, v1;
        v0[0] = f2bf(a.x); v0[1] = f2bf(a.y); v0[2] = f2bf(a.z); v0[3] = f2bf(a.w);
        v0[4] = f2bf(b.x); v0[5] = f2bf(b.y); v0[6] = f2bf(b.z); v0[7] = f2bf(b.w);
        v1[0] = f2bf(c.x); v1[1] = f2bf(c.y); v1[2] = f2bf(c.z); v1[3] = f2bf(c.w);
        v1[4] = f2bf(d.x); v1[5] = f2bf(d.y); v1[6] = f2bf(d.z); v1[7] = f2bf(d.w);
        ((short8*)dst)[i * 2]     = v0;
        ((short8*)dst)[i * 2 + 1] = v1;
    } else {
        // wtrans: 32x32 tile transpose, z picks Wq/Wk/Wv
        int t = bid - CONV_END;
        int z = t >> 10, r2 = t & 1023;
        const float* W = (z == 0) ? Wq : (z == 1) ? Wk : Wv;
        short* dst = Wt + (size_t)z * HD * FD;
        int h0 = (r2 & 31) * 32, f0 = (r2 >> 5) * 32;
        int tx = tid & 31, ty = tid >> 5;
        for (int j = ty; j < 32; j += 8)
            tile[j][tx] = W[(size_t)(f0 + j) * HD + h0 + tx];
        __syncthreads();
        for (int j = ty; j < 32; j += 8)
            dst[(size_t)(h0 + j) * FD + f0 + tx] = f2bf(tile[tx][j]);
    }
}

// ---- Q/K projections: 256x256 tiles over [16384 x 1024] ----
__global__ __launch_bounds__(512, 2) void projqk_kernel(const short* __restrict__ Xq,
                                                        const short* __restrict__ Xe,
                                                        const short* __restrict__ Wt3,
                                                        const float* __restrict__ bq,
                                                        const float* __restrict__ bk,
                                                        short* __restrict__ Q,
                                                        short* __restrict__ K) {
    extern __shared__ char smem[];
    int tid = threadIdx.x;
    int p = blockIdx.z;
    const short* X = p ? Xe : Xq;
    const short* Wt = Wt3 + (size_t)p * HD * FD;
    const float* bias = p ? bk : bq;
    short* O = p ? K : Q;
    int bid = blockIdx.x;                   // XCD swizzle: m-groups bound to XCDs
    int xcd = bid & 7, idx = bid >> 3;
    int n_t = idx & 3, m_t = (idx >> 2) * 8 + xcd;
    int tile_m = m_t * 256, tile_n = n_t * 256;
    f32x4 acc[8][4] = {};
    gemm256_core<false>(X + (size_t)tile_m * FD, Wt + (size_t)tile_n * FD, FD, FD, smem, acc, tid);
    int wid = tid >> 6, lane = tid & 63;
    int wm = wid >> 2, wn = wid & 3;
    int row0 = tile_m + wm * 128 + ((lane >> 4) << 2);
    int col0 = tile_n + wn * 64 + (lane & 15);
    // n-INNER store order (write-combine; kills the 2x WRITE_SIZE amplification)
    float bv4[4];
#pragma unroll
    for (int n = 0; n < 4; ++n) bv4[n] = bias[col0 + n * 16];
#pragma unroll
    for (int m = 0; m < 8; ++m)
#pragma unroll
        for (int r = 0; r < 4; ++r) {
            size_t rowb = (size_t)(row0 + m * 16 + r) * HD;
#pragma unroll
            for (int n = 0; n < 4; ++n)
                O[rowb + col0 + n * 16] = f2bf(acc[m][n][r] + bv4[n]);
        }
}

// ---- V projection, transposed natively: Vt[b][h][t] = Wtv[h,:].Xe[b,t,:] + bv[h], fp16 out ----
__global__ __launch_bounds__(512, 2) void projv_kernel(const short* __restrict__ Xe,
                                                       const short* __restrict__ Wtv,
                                                       const float* __restrict__ bv,
                                                       short* __restrict__ Vt) {
    extern __shared__ char smem[];
    int tid = threadIdx.x;
    int bid = blockIdx.x;
    int b = bid & 7, i = bid >> 3;          // batch -> XCD binding
    int m_t = i & 3, n_t = i >> 2;          // m over HD (4), n over TKv (8)
    int tile_m = m_t * 256, tile_n = n_t * 256;
    const short* Xb = Xe + (size_t)b * TKv * FD;
    f32x4 acc[8][4] = {};
    gemm256_core<false>(Wtv + (size_t)tile_m * FD, Xb + (size_t)tile_n * FD, FD, FD, smem, acc, tid);
    short* Ob = Vt + (size_t)b * HD * TKv;
    int wid = tid >> 6, lane = tid & 63;
    int wm = wid >> 2, wn = wid & 3;
    int row0 = tile_m + wm * 128 + ((lane >> 4) << 2);
    int col0 = tile_n + wn * 64 + (lane & 15);
#pragma unroll
    for (int m = 0; m < 8; ++m)
#pragma unroll
        for (int r = 0; r < 4; ++r) {
            int gm = row0 + m * 16 + r;     // h
            float bv_ = bv[gm];
#pragma unroll
            for (int n = 0; n < 4; ++n) {
                union { _Float16 h; short s; } cv;
                cv.h = (_Float16)(acc[m][n][r] + bv_);
                Ob[(size_t)gm * TKv + col0 + n * 16] = cv.s;
            }
        }
}

// ---- score: P' = mask ? exp(QK/32 - 4) : 0 (fp16), row partials -> atomicAdd L ----
__global__ __launch_bounds__(512, 2) void score_kernel(const short* __restrict__ Q,
                                                       const short* __restrict__ K,
                                                       const unsigned long long* __restrict__ Mbits,
                                                       short* __restrict__ S,
                                                       float* __restrict__ L) {
    extern __shared__ char smem[];
    int tid = threadIdx.x;
    int bid = blockIdx.x;
    int b = bid & 7, i = bid >> 3;          // batch -> XCD binding
    int n_t = i & 7, m_t = i >> 3;
    int tile_m = m_t * 256, tile_n = n_t * 256;
    const short* Aq = Q + (size_t)b * TQv * HD;
    const short* Bk = K + (size_t)b * TKv * HD;
    f32x4 acc[8][4] = {};
    gemm256_core<false>(Aq + (size_t)tile_m * HD, Bk + (size_t)tile_n * HD, HD, HD, smem, acc, tid);
    short* Sb = S + (size_t)b * TQv * TKv;
    float* Lb = L + (size_t)b * TQv;
    int wid = tid >> 6, lane = tid & 63;
    int wm = wid >> 2, wn = wid & 3;
    int l15 = lane & 15;
    int row0 = tile_m + wm * 128 + ((lane >> 4) << 2);
    int col0 = tile_n + wn * 64 + l15;

    // stage this block's Mbits slab (256 rows x 4 words = 8 KB) into now-free LDS
    // with one coalesced global_load_lds burst (kills the serialized load chain).
    {
        const unsigned long long* MbT = Mbits + (size_t)b * TQv * (TKv / 64)
                                        + (size_t)tile_m * (TKv / 64) + (tile_n >> 6);
        async16((const short*)(MbT + (size_t)(tid >> 1) * (TKv / 64) + (size_t)(tid & 1) * 2),
                (short*)smem + wid * 512);
    }
    __syncthreads();   // drains vmcnt(0)+lgkmcnt(0): slab landed, visible to all

#pragma unroll
    for (int m = 0; m < 8; ++m)
#pragma unroll
        for (int r = 0; r < 4; ++r) {
            int rl = wm * 128 + m * 16 + ((lane >> 4) << 2) + r;   // row - tile_m
            int gm = tile_m + rl;
            unsigned long long bits = *(const unsigned long long*)(smem + rl * 32 + wn * 8);
            float rs = 0.f;
#pragma unroll
            for (int n = 0; n < 4; ++n) {
                // exp2((acc/32 - 4)*log2e) folded: exp2(acc*0.04508422 - 5.77078016)
                float pv = ((bits >> (n * 16 + l15)) & 1ULL)
                               ? exp2f(acc[m][n][r] * 0.04508422f - 5.77078016f) : 0.f;
                rs += pv;
                union { _Float16 h; short sh; } cv;
                cv.h = (_Float16)pv;
                Sb[(size_t)gm * TKv + col0 + n * 16] = cv.sh;
            }
            for (int sh = 1; sh < 16; sh <<= 1) rs += __shfl_xor(rs, sh);
            if (l15 == 0) atomicAdd(&Lb[gm], rs);
        }
}

// ---- pv: O = (P' . Vt^T) / L, fp16 MFMA, fp32 out ----
__global__ __launch_bounds__(512, 2) void pv_kernel(const short* __restrict__ P,
                                                    const short* __restrict__ Vt,
                                                    const float* __restrict__ L,
                                                    float* __restrict__ Out) {
    extern __shared__ char smem[];
    int tid = threadIdx.x;
    int bid = blockIdx.x;
    int b = bid & 7, i = bid >> 3;          // batch -> XCD binding
    int n_t = i & 3, m_t = i >> 2;          // n over HD (4), m over TQv (8)
    int tile_m = m_t * 256, tile_n = n_t * 256;
    const short* Ap = P + (size_t)b * TQv * TKv;
    const short* Bv = Vt + (size_t)b * HD * TKv;
    const float* Lb = L + (size_t)b * TQv;
    f32x4 acc[8][4] = {};
    gemm256_core<true>(Ap + (size_t)tile_m * TKv, Bv + (size_t)tile_n * TKv, TKv, TKv, smem, acc, tid);
    float* Ob = Out + (size_t)b * TQv * HD;
    int wid = tid >> 6, lane = tid & 63;
    int wm = wid >> 2, wn = wid & 3;
    int row0 = tile_m + wm * 128 + ((lane >> 4) << 2);
    int col0 = tile_n + wn * 64 + (lane & 15);

    // stage the 256-row L slab (1 KB) into free LDS via wave 0 (broadcast reads after)
    if (tid < 64)
        async16((const short*)(Lb + tile_m + tid * 4), (short*)smem);
    __syncthreads();

#pragma unroll
    for (int m = 0; m < 8; ++m)
#pragma unroll
        for (int r = 0; r < 4; ++r) {
            int rl = wm * 128 + m * 16 + ((lane >> 4) << 2) + r;   // row - tile_m
            int gm = tile_m + rl;
            float l = *(const float*)(smem + rl * 4);
            float inv = (l > 0.f) ? 1.f / l : 0.f;
#pragma unroll
            for (int n = 0; n < 4; ++n)
                Ob[(size_t)gm * HD + col0 + n * 16] = acc[m][n][r] * inv;
        }
}

extern "C" void kernel_launch(void* const* d_in, const int* in_sizes, int n_in,
                              void* d_out, int out_size, void* d_ws, size_t ws_size,
                              hipStream_t stream) {
    const float* query = (const float*)d_in[0];
    const float* enc   = (const float*)d_in[1];
    const int*   mask  = (const int*)d_in[2];
    const float* Wq    = (const float*)d_in[3];
    const float* bq    = (const float*)d_in[4];
    const float* Wk    = (const float*)d_in[5];
    const float* bk    = (const float*)d_in[6];
    const float* Wv    = (const float*)d_in[7];
    const float* bv    = (const float*)d_in[8];
    float* out = (float*)d_out;

    // workspace layout (bytes):
    //   Mbits [0,4MB), L [4MB,+64KB), Wt [4.0625MB,+6.29MB), Xq/Xe, S aliases Xq/Xe,
    //   Qb, Kb, Vt.
    char* ws = (char*)d_ws;
    unsigned long long* Mbits = (unsigned long long*)(ws);
    float* L   = (float*)(ws + 4194304);
    short* Wt  = (short*)(ws + 4259840);
    short* Xq  = (short*)(ws + 10551296);
    short* Xe  = (short*)(ws + 44105728);
    short* S   = (short*)(ws + 10551296);      // aliases Xq,Xe (dead after projqk/projv)
    short* Qb  = (short*)(ws + 77660160);
    short* Kb  = (short*)(ws + 111214592);
    short* Vt  = (short*)(ws + 144769024);
    (void)in_sizes; (void)n_in; (void)out_size; (void)ws_size;

    // 128 KiB dynamic LDS opt-in (one-time; not a stream op, graph-capture safe)
    static bool inited = false;
    if (!inited) {
        hipFuncSetAttribute((const void*)projqk_kernel, hipFuncAttributeMaxDynamicSharedMemorySize, 131072);
        hipFuncSetAttribute((const void*)projv_kernel,  hipFuncAttributeMaxDynamicSharedMemorySize, 131072);
        hipFuncSetAttribute((const void*)score_kernel,  hipFuncAttributeMaxDynamicSharedMemorySize, 131072);
        hipFuncSetAttribute((const void*)pv_kernel,     hipFuncAttributeMaxDynamicSharedMemorySize, 131072);
        inited = true;
    }

    prep_kernel<<<dim3(MB_BLKS + CONV_BLKS + 3072), 256, 0, stream>>>(
        query, enc, Wq, Wk, Wv, mask, Xq, Xe, Wt, Mbits, L);
    projqk_kernel<<<dim3(256, 1, 2), 512, 131072, stream>>>(Xq, Xe, Wt, bq, bk, Qb, Kb);
    projv_kernel<<<dim3(256), 512, 131072, stream>>>(Xe, Wt + (size_t)2 * HD * FD, bv, Vt);
    score_kernel<<<dim3(512), 512, 131072, stream>>>(Qb, Kb, Mbits, S, L);
    pv_kernel<<<dim3(256), 512, 131072, stream>>>(S, Vt, L, out);
}